// Round 2
// baseline (459.952 us; speedup 1.0000x reference)
//
#include <hip/hip_runtime.h>
#include <stdint.h>

// BiRealConv2d: y = conv2d(sign(x), scale[o]*sign(w)), NCHW, 3x3, pad 1.
// Exact integer XNOR-popcount formulation.
// R2: (a) pack restructured: 32 ch/thread, 4-wave blocks -> 28 waves/SIMD
//     (b) conv: x-taps pinned in VGPRs via asm barrier (R1 had VGPR=32 ->
//         compiler re-loaded taps every o-iter, 2.6x VALU bloat)
//     (c) epilogue: out = scale * (c2[o][pat] - 2*pc), c2 precomputed.

#define HH 112
#define WW 112
#define CC 128
#define OO 128
#define NN 32
#define HP 114   // padded (halo = zeroed -> corrected via c2 table)
#define WP 114

// ---------------- pass 1: pack sign(x) into 128-bit masks per pixel ----------------
// block 256 = 4 waves; lane = pixel-in-tile, grp = 32-channel group.
__global__ __launch_bounds__(256) void pack_x_kernel(const float* __restrict__ x,
                                                     uint32_t* __restrict__ xb32) {
  int t = threadIdx.x;
  int lane = t & 63;
  int grp = t >> 6;                 // 0..3 -> channels [grp*32, grp*32+32)
  int w = blockIdx.x * 64 + lane;
  int h = blockIdx.y;
  int n = blockIdx.z;
  if (w >= WW) return;
  const float* xp = x + (((size_t)n * CC + grp * 32) * HH + h) * WW + w;
  uint32_t mm = 0u;
#pragma unroll
  for (int b = 0; b < 32; b++) {
    float v = xp[(size_t)b * (HH * WW)];
    mm |= (v > 0.0f) ? (1u << b) : 0u;   // bit=1 -> +1, bit=0 -> -1
  }
  xb32[(((size_t)n * HP + (h + 1)) * WP + (w + 1)) * 4 + grp] = mm;
}

// ---------------- pass 0: weight scale + bitmasks + border table -------------------
__global__ __launch_bounds__(256) void prep_w_kernel(const float* __restrict__ wt,
                                                     uint64_t* __restrict__ wbits,
                                                     float* __restrict__ scale,
                                                     int* __restrict__ c2) {
  int o = blockIdx.x;
  const float* wo = wt + (size_t)o * (CC * 9);
  __shared__ unsigned int bits[9][4];
  __shared__ float red[256];
  int t = threadIdx.x;
  if (t < 36) ((unsigned int*)bits)[t] = 0u;
  __syncthreads();
  float s = 0.0f;
  for (int idx = t; idx < CC * 9; idx += 256) {
    float v = wo[idx];
    s += fabsf(v);
    int ci = idx / 9, tap = idx % 9;      // OIHW: [i][kh][kw], tap = kh*3+kw
    if (v > 0.0f) atomicOr(&bits[tap][ci >> 5], 1u << (ci & 31));
  }
  red[t] = s;
  __syncthreads();
  for (int st = 128; st > 0; st >>= 1) {
    if (t < st) red[t] += red[t + st];
    __syncthreads();
  }
  if (t == 0) {
    scale[o] = red[0] * (1.0f / 1152.0f);
    int c[9];
#pragma unroll
    for (int tap = 0; tap < 9; tap++) {
      uint64_t lo = (uint64_t)bits[tap][0] | ((uint64_t)bits[tap][1] << 32);
      uint64_t hi = (uint64_t)bits[tap][2] | ((uint64_t)bits[tap][3] << 32);
      wbits[o * 18 + tap * 2]     = lo;
      wbits[o * 18 + tap * 2 + 1] = hi;
      c[tap] = 128 - 2 * (__builtin_popcountll(lo) + __builtin_popcountll(hi));
    }
    // 9 border patterns: pat = ph*3+pw; 0=low edge,1=interior,2=high edge.
    // c2 = 1152 - (spurious halo contribution), so dot = c2 - 2*popc.
    for (int ph = 0; ph < 3; ph++)
      for (int pw = 0; pw < 3; pw++) {
        int sum = 0;
        for (int tap = 0; tap < 9; tap++) {
          int kh = tap / 3, kw = tap % 3;
          bool inv = (ph == 0 && kh == 0) || (ph == 2 && kh == 2) ||
                     (pw == 0 && kw == 0) || (pw == 2 && kw == 2);
          if (inv) sum += c[tap];
        }
        c2[o * 9 + ph * 3 + pw] = 1152 - sum;
      }
  }
}

// ---------------- pass 2: XNOR-popcount conv -------------------------------------
__global__ __launch_bounds__(256) void conv_kernel(const uint64_t* __restrict__ xb,
                                                   const uint64_t* __restrict__ wbits,
                                                   const float* __restrict__ scale,
                                                   const int* __restrict__ c2,
                                                   float* __restrict__ out) {
  int t = threadIdx.x;
  // o-group is wave-uniform; readfirstlane guarantees SGPR -> s_load for wbits/scale.
  int og = __builtin_amdgcn_readfirstlane(t >> 6);
  int wl = t & 63;
  int w = blockIdx.x * 64 + wl;
  int h = blockIdx.y;
  int n = blockIdx.z;
  if (w >= WW) return;
  int ph = (h == 0) ? 0 : ((h == HH - 1) ? 2 : 1);
  int pw = (w == 0) ? 0 : ((w == WW - 1) ? 2 : 1);
  int pat = ph * 3 + pw;

  // 9 taps x 128 bits = 18 u64, loaded ONCE and pinned in VGPRs.
  const uint64_t* xbase = xb + (((size_t)n * HP + h) * WP + w) * 2;
  uint64_t xv[18];
#pragma unroll
  for (int dh = 0; dh < 3; dh++)
#pragma unroll
    for (int dw = 0; dw < 3; dw++) {
      const ulonglong2 v = *(const ulonglong2*)(xbase + ((size_t)dh * WP + dw) * 2);
      xv[(dh * 3 + dw) * 2]     = v.x;
      xv[(dh * 3 + dw) * 2 + 1] = v.y;
    }
  // Opaque-touch: forbids rematerializing the loads inside the o-loop.
#pragma unroll
  for (int i = 0; i < 18; i++) asm volatile("" : "+v"(xv[i]));

  size_t obase = (((size_t)(n * OO + og * 32)) * HH + h) * WW + w;
  const int* c2p = c2 + pat;
#pragma unroll 4
  for (int j = 0; j < 32; j++) {
    int o = (og << 5) + j;                     // wave-uniform
    const uint64_t* wb = wbits + o * 18;
    int pc = 0;
#pragma unroll
    for (int tap = 0; tap < 18; tap++)
      pc += __builtin_popcountll(xv[tap] ^ wb[tap]);
    out[obase] = scale[o] * (float)(c2p[o * 9] - 2 * pc);
    obase += (size_t)HH * WW;
  }
}

extern "C" void kernel_launch(void* const* d_in, const int* in_sizes, int n_in,
                              void* d_out, int out_size, void* d_ws, size_t ws_size,
                              hipStream_t stream) {
  const float* x  = (const float*)d_in[0];
  const float* wt = (const float*)d_in[1];
  float* out = (float*)d_out;

  char* ws = (char*)d_ws;
  size_t xb_elems = (size_t)NN * HP * WP * 2;       // u64 count (6.65 MB)
  uint64_t* xb    = (uint64_t*)ws;
  size_t off = xb_elems * 8;
  uint64_t* wbits = (uint64_t*)(ws + off); off += (size_t)OO * 18 * 8;
  float* scale    = (float*)(ws + off);    off += (size_t)OO * 4;
  int* c2         = (int*)(ws + off);      off += (size_t)OO * 9 * 4;

  hipMemsetAsync(xb, 0, xb_elems * 8, stream);   // zero halo
  hipLaunchKernelGGL(pack_x_kernel, dim3(2, HH, NN), dim3(256), 0, stream,
                     x, (uint32_t*)xb);
  hipLaunchKernelGGL(prep_w_kernel, dim3(OO), dim3(256), 0, stream, wt, wbits, scale, c2);
  hipLaunchKernelGGL(conv_kernel, dim3(2, HH, NN), dim3(256), 0, stream,
                     xb, wbits, scale, c2, out);
}